// Round 8
// baseline (3096.977 us; speedup 1.0000x reference)
//
#include <hip/hip_runtime.h>
#include <hip/hip_bf16.h>
#include <stdint.h>

// ------------------------------------------------------------------
// ws layout (float offsets)
#define WS_MODE  0
#define WS_PX    16        // 768
#define WS_PY    784       // 768
#define WS_PZ    1552      // 768
#define WS_TVEC  2320      // 2*8
#define WS_HKEY  2336      // 4 u32
#define WS_FEATT 2352      // 16*768 transposed [c][j]
#define WS_W0L0  14640     // 24*32
#define WS_B0L0  15408     // 32
#define WS_W0L1  15440     // 24*32
#define WS_W1L0  16208     // 64
#define WS_B1L0  16272     // 1
#define WS_W1L1  16288     // 96*2
#define WS_R00T  16480     // 24*32 transposed [c][b]
#define WS_R01T  17248     // 24*32
#define WS_R1F   18016     // 5*1024  (R1_00,R1_11d,R1_01,R1_10,R1_11c)
#define WS_GT    23136     // 768*352  G tables [j][comp(11)][b(32)]
#define WS_PB    293472    // 768*96*4 pass-B partials [i][chunk]
#define WS_LG    735840    // 2*768 per-i logp

#define OUT_LOGP 2304
#define OUT_YS   2305

__device__ __forceinline__ float ld_in(const void* p, int idx, int bf) {
  if (bf) return __bfloat162float(((const __hip_bfloat16*)p)[idx]);
  return ((const float*)p)[idx];
}
__device__ __forceinline__ void store_out(void* out, int idx, float v, int bf) {
  if (bf) ((__hip_bfloat16*)out)[idx] = __float2bfloat16(v);
  else ((float*)out)[idx] = v;
}

// JAX threefry2x32 (20 rounds)
__device__ __forceinline__ void tf2x32(uint32_t k0, uint32_t k1, uint32_t x0, uint32_t x1,
                                       uint32_t& o0, uint32_t& o1) {
  uint32_t ks[3] = {k0, k1, k0 ^ k1 ^ 0x1BD11BDAu};
  x0 += ks[0]; x1 += ks[1];
  const int R0[4] = {13, 15, 26, 6};
  const int R1[4] = {17, 29, 16, 24};
#pragma unroll
  for (int i = 0; i < 5; ++i) {
    const int* r = (i & 1) ? R1 : R0;
#pragma unroll
    for (int q = 0; q < 4; ++q) {
      x0 += x1;
      x1 = (x1 << r[q]) | (x1 >> (32 - r[q]));
      x1 ^= x0;
    }
    x0 += ks[(i + 1) % 3];
    x1 += ks[(i + 2) % 3] + (uint32_t)(i + 1);
  }
  o0 = x0; o1 = x1;
}

// XLA ErfInv (f32, Giles)
__device__ __forceinline__ float erfinv_f(float x) {
  float w = -log1pf(-x * x);
  float p;
  if (w < 5.0f) {
    w -= 2.5f;
    p = 2.81022636e-08f;
    p = fmaf(p, w, 3.43273939e-07f);
    p = fmaf(p, w, -3.5233877e-06f);
    p = fmaf(p, w, -4.39150654e-06f);
    p = fmaf(p, w, 0.00021858087f);
    p = fmaf(p, w, -0.00125372503f);
    p = fmaf(p, w, -0.00417768164f);
    p = fmaf(p, w, 0.246640727f);
    p = fmaf(p, w, 1.50140941f);
  } else {
    w = sqrtf(w) - 3.0f;
    p = -0.000200214257f;
    p = fmaf(p, w, 0.000100950558f);
    p = fmaf(p, w, 0.00134934322f);
    p = fmaf(p, w, -0.00367342844f);
    p = fmaf(p, w, 0.00573950773f);
    p = fmaf(p, w, -0.0076224613f);
    p = fmaf(p, w, 0.00943887047f);
    p = fmaf(p, w, 1.00167406f);
    p = fmaf(p, w, 2.83297682f);
  }
  return p * x;
}

// ------------------------------------------------------------------
// dtype probe: every block re-derives bf from the positions buffer (L2-hot).
__device__ int probe_bf(const void* pos, int tid) {
  __shared__ int s_ok;
  if (tid == 0) s_ok = 1;
  __syncthreads();
  const unsigned short* ph = (const unsigned short*)pos;
  int ok = 1;
  for (int e = tid; e < 2304; e += 256) {
    unsigned short v = ph[e];
    if ((v & 0x7fffu) != 0u) {
      int ex = (v >> 7) & 0xff;
      if (ex < 40 || ex > 140) ok = 0;
    }
  }
  if (!ok) atomicAnd(&s_ok, 0);
  __syncthreads();
  return s_ok;
}

// ------------------------------------------------------------------
// k_init: 16 role-based blocks.
__global__ __launch_bounds__(256) void k_init(
    const void* pos, const void* feats, const void* tw1, const void* tb1,
    const void* tw2, const void* tb2, const void* R000, const void* R001,
    const void* W0L0, const void* b0L0, const void* W0L1,
    const void* R100, const void* R111d, const void* R101,
    const void* R110, const void* R111c,
    const void* W1L0, const void* b1L0, const void* W1L1,
    const int* seedp, float* ws, void* out) {
  int tid = threadIdx.x, b = blockIdx.x;
  int bf = probe_bf(pos, tid);
  switch (b) {
    case 0: {  // mode flag + tvec + PRNG
      if (tid == 0) ws[WS_MODE] = (float)bf;
      if (tid < 16) {
        int it = tid >> 3, d = tid & 7;
        float t = (float)(it + 1) * 0.5f;
        float a = ld_in(tb2, d, bf);
        for (int h = 0; h < 32; ++h) {
          float pre = fmaf(t, ld_in(tw1, h, bf), ld_in(tb1, h, bf));
          float th = pre / (1.0f + expf(-pre));
          a = fmaf(th, ld_in(tw2, h * 8 + d, bf), a);
        }
        ws[WS_TVEC + it * 8 + d] = a;
      }
      if (tid == 32) {  // PRNG: partitionable split chain
        uint32_t k0 = 0u, k1 = (uint32_t)seedp[0];
        uint32_t* hk = (uint32_t*)(ws + WS_HKEY);
        uint32_t a0, a1, b0, b1, c0, c1;
        tf2x32(k0, k1, 0u, 0u, a0, a1);
        tf2x32(k0, k1, 0u, 1u, b0, b1);
        hk[0] = b0; hk[1] = b1;
        tf2x32(a0, a1, 0u, 1u, c0, c1);
        hk[2] = c0; hk[3] = c1;
      }
      break;
    }
    case 1: {  // positions SoA
      for (int n = tid; n < 768; n += 256) {
        ws[WS_PX + n] = ld_in(pos, n * 3 + 0, bf);
        ws[WS_PY + n] = ld_in(pos, n * 3 + 1, bf);
        ws[WS_PZ + n] = ld_in(pos, n * 3 + 2, bf);
      }
      break;
    }
    case 2: case 3: {  // out_ys[0] passthrough
      for (int e = (b - 2) * 1152 + tid; e < (b - 1) * 1152; e += 256)
        store_out(out, OUT_YS + e, ld_in(pos, e, bf), bf);
      break;
    }
    case 4: case 5: case 6: case 7:
    case 8: case 9: case 10: case 11: {  // feats transpose, 1536 each
      int base = (b - 4) * 1536;
      for (int e = base + tid; e < base + 1536; e += 256) {
        int j = e >> 4, c = e & 15;
        ws[WS_FEATT + c * 768 + j] = ld_in(feats, e, bf);
      }
      break;
    }
    case 12: {  // layer-0 tables
      for (int e = tid; e < 768; e += 256) {
        ws[WS_W0L0 + e] = ld_in(W0L0, e, bf);
        ws[WS_W0L1 + e] = ld_in(W0L1, e, bf);
        int bb = e / 24, c = e % 24;
        ws[WS_R00T + c * 32 + bb] = ld_in(R000, e, bf);
        ws[WS_R01T + c * 32 + bb] = ld_in(R001, e, bf);
      }
      break;
    }
    case 13: {  // small tables
      if (tid < 32) ws[WS_B0L0 + tid] = ld_in(b0L0, tid, bf);
      if (tid >= 64 && tid < 128) ws[WS_W1L0 + tid - 64] = ld_in(W1L0, tid - 64, bf);
      if (tid >= 128 && tid < 192) {
        for (int e = tid - 128; e < 192; e += 64) ws[WS_W1L1 + e] = ld_in(W1L1, e, bf);
      }
      if (tid == 33) ws[WS_B1L0] = ld_in(b1L0, 0, bf);
      break;
    }
    case 14: case 15: {  // R1 tables, 2560 each
      int base = (b - 14) * 2560;
      const void* tabs[5] = {R100, R111d, R101, R110, R111c};
      for (int e = base + tid; e < base + 2560; e += 256) {
        int tab = e >> 10, off = e & 1023;
        ws[WS_R1F + e] = ld_in(tabs[tab], off, bf);
      }
      break;
    }
  }
}

// ------------------------------------------------------------------
// Pass A v6 (fused): one block per i. 384 threads = 6 waves, each wave one
// (CH, jset) segment, 4 j per lane. In-block reduce + inline epilogue
// (swish/gate + layer-1 fold) -> writes G[i][352] directly.
__global__ __launch_bounds__(384, 2) void k_passA(const float* __restrict__ ws,
                                                  float* __restrict__ wso, int it) {
  int i = blockIdx.x;
  int tid = threadIdx.x;
  int wave = tid >> 6, lane = tid & 63;
  int CH = wave / 3, jset = wave % 3;   // wave-uniform
  float pix = ws[WS_PX + i], piy = ws[WS_PY + i], piz = ws[WS_PZ + i];

  const float* __restrict__ rt0 = ws + WS_R00T + CH * 384;
  const float* __restrict__ rt1 = ws + WS_R01T + CH * 384;

  float tvv[8];
#pragma unroll
  for (int d = 0; d < 8; ++d) tvv[d] = ws[WS_TVEC + it * 8 + d];

  float out[48];
#pragma unroll
  for (int k = 0; k < 48; ++k) out[k] = 0.0f;

#pragma unroll
  for (int q = 0; q < 4; ++q) {
    int j = jset * 256 + q * 64 + lane;
    float dx = pix - ws[WS_PX + j];
    float dy = piy - ws[WS_PY + j];
    float dz = piz - ws[WS_PZ + j];
    float n2 = dx * dx + dy * dy + dz * dz;
    float nrm = sqrtf(n2 + 1e-8f);
    float invn = 1.0f / nrm;
    float msk = (n2 > 1e-10f) ? invn : 0.0f;
    float ux = dx * invn, uy = dy * invn, uz = dz * invn;
    float sn, cs;
    sincosf(nrm * 0.52359879f, &sn, &cs);
    float rbf[32];
    float twoc = 2.0f * cs;
    rbf[0] = sn * msk;
    float skm1 = 0.0f, sk = rbf[0];
#pragma unroll
    for (int k = 1; k < 32; ++k) {       // sin(k*theta)/safe via Chebyshev
      float s2 = fmaf(twoc, sk, -skm1);
      skm1 = sk; sk = s2; rbf[k] = sk;
    }
    float fv[12];
    if (CH == 0) {
#pragma unroll
      for (int c = 0; c < 12; ++c) fv[c] = ws[WS_FEATT + c * 768 + j];
    } else {
#pragma unroll
      for (int c = 0; c < 4; ++c) fv[c] = ws[WS_FEATT + (12 + c) * 768 + j];
#pragma unroll
      for (int c = 4; c < 12; ++c) fv[c] = tvv[c - 4];
    }
#pragma unroll
    for (int c = 0; c < 12; ++c) {
      float rw0 = 0.0f, rw1 = 0.0f;
#pragma unroll
      for (int bq = 0; bq < 32; ++bq) {
        rw0 = fmaf(rbf[bq], rt0[c * 32 + bq], rw0);
        rw1 = fmaf(rbf[bq], rt1[c * 32 + bq], rw1);
      }
      float f = fv[c];
      out[c] = fmaf(rw0, f, out[c]);
      float pp = rw1 * f;
      out[12 + 3 * c + 0] = fmaf(pp, ux, out[12 + 3 * c + 0]);
      out[12 + 3 * c + 1] = fmaf(pp, uy, out[12 + 3 * c + 1]);
      out[12 + 3 * c + 2] = fmaf(pp, uz, out[12 + 3 * c + 2]);
    }
  }

  // 2-step butterfly (4-lane groups), then segment columns into LDS
#pragma unroll
  for (int k = 0; k < 48; ++k) {
    float v = out[k];
    v += __shfl_xor(v, 1);
    v += __shfl_xor(v, 2);
    out[k] = v;
  }
  __shared__ float P[48][105];
  __shared__ float oall[96];
  __shared__ float wf[11][32];
  if ((lane & 3) == 0) {
    int col = wave * 16 + (lane >> 2);
#pragma unroll
    for (int k = 0; k < 48; ++k) P[k][col] = out[k];
  }
  __syncthreads();
  // reduce 48 cols per (ch, row), store into oall with passA2's indexing
  if (tid < 96) {
    int ch = tid / 48, r = tid % 48;
    float s = 0.0f;
#pragma unroll 8
    for (int c2 = 0; c2 < 48; ++c2) s += P[r][ch * 48 + c2];
    int t;
    if (r < 12) t = ch * 12 + r;
    else { int cc = (r - 12) / 3, m = (r - 12) % 3; t = 24 + 3 * (ch * 12 + cc) + m; }
    oall[t] = s;
  }
  __syncthreads();
  // epilogue: swish/gate + per-h weight folding (h = 0..31)
  if (tid < 32) {
    int h = tid;
    float x0p = ws[WS_B0L0 + h];
#pragma unroll
    for (int c = 0; c < 24; ++c) x0p = fmaf(oall[c], ws[WS_W0L0 + c * 32 + h], x0p);
    float f0b = x0p / (1.0f + expf(-x0p));   // swish
    float v0 = 0.0f, v1 = 0.0f, v2 = 0.0f;
#pragma unroll
    for (int c = 0; c < 24; ++c) {
      float w = ws[WS_W0L1 + c * 32 + h];
      v0 = fmaf(oall[24 + 3 * c + 0], w, v0);
      v1 = fmaf(oall[24 + 3 * c + 1], w, v1);
      v2 = fmaf(oall[24 + 3 * c + 2], w, v2);
    }
    float g = 1.0f / (1.0f + expf(-sqrtf(v0 * v0 + v1 * v1 + v2 * v2 + 1e-8f)));
    float x1m0 = v0 * g, x1m1 = v1 * g, x1m2 = v2 * g;
    float WA = ws[WS_W1L0 + h];
    float WB = ws[WS_W1L0 + 32 + h];
    float Wa = ws[WS_W1L1 + h * 2 + 1];
    float Wb = ws[WS_W1L1 + (32 + h) * 2 + 1];
    float Wc = ws[WS_W1L1 + (64 + h) * 2 + 1];
    wf[0][h] = WA * f0b;
    wf[1][h] = WB * x1m0; wf[2][h] = WB * x1m1; wf[3][h] = WB * x1m2;
    wf[4][h] = Wa * f0b;
    wf[5][h] = Wb * x1m0; wf[6][h] = Wb * x1m1; wf[7][h] = Wb * x1m2;
    wf[8][h] = Wc * x1m0; wf[9][h] = Wc * x1m1; wf[10][h] = Wc * x1m2;
  }
  __syncthreads();
  // layer-1 fold: G[i][comp*32 + b]
  if (tid < 352) {
    int comp = tid >> 5, b = tid & 31;
    int tab = (comp == 0) ? 0 : (comp < 4) ? 1 : (comp == 4) ? 2 : (comp < 8) ? 3 : 4;
    const float* rrow = ws + WS_R1F + tab * 1024 + b * 32;
    float gacc = 0.0f;
#pragma unroll
    for (int c = 0; c < 32; ++c) gacc = fmaf(rrow[c], wf[comp][c], gacc);
    wso[WS_GT + i * 352 + tid] = gacc;
  }
}

// ------------------------------------------------------------------
// Pass B: lanes own i, j uniform per step (scalar G/pos loads).
__global__ __launch_bounds__(256) void k_passB(const float* __restrict__ ws,
                                               float* __restrict__ wso) {
  int i = blockIdx.y * 256 + threadIdx.x;
  int chunk = blockIdx.x;                    // 0..95, 8 j per chunk
  float pix = ws[WS_PX + i], piy = ws[WS_PY + i], piz = ws[WS_PZ + i];
  float y0 = 0.0f, t0 = 0.0f, t1 = 0.0f, t2 = 0.0f;
  for (int q = 0; q < 8; ++q) {
    int j = chunk * 8 + q;
    float dx = pix - ws[WS_PX + j];
    float dy = piy - ws[WS_PY + j];
    float dz = piz - ws[WS_PZ + j];
    float n2 = dx * dx + dy * dy + dz * dz;
    float nrm = sqrtf(n2 + 1e-8f);
    float invn = 1.0f / nrm;
    float msk = (n2 > 1e-10f) ? invn : 0.0f;
    float ux = dx * invn, uy = dy * invn, uz = dz * invn;
    float sn, cs;
    sincosf(nrm * 0.52359879f, &sn, &cs);
    float rbf[32];
    float twoc = 2.0f * cs;
    rbf[0] = sn * msk;
    float skm1 = 0.0f, sk = rbf[0];
#pragma unroll
    for (int k = 1; k < 32; ++k) {
      float s2 = fmaf(twoc, sk, -skm1);
      skm1 = sk; sk = s2; rbf[k] = sk;
    }
    const float* g = ws + WS_GT + j * 352;
    float sA = 0.f, vB0 = 0.f, vB1 = 0.f, vB2 = 0.f, sC = 0.f;
    float vD0 = 0.f, vD1 = 0.f, vD2 = 0.f, vE0 = 0.f, vE1 = 0.f, vE2 = 0.f;
#pragma unroll
    for (int b = 0; b < 32; ++b) {
      float r = rbf[b];
      sA  = fmaf(r, g[0 * 32 + b], sA);
      vB0 = fmaf(r, g[1 * 32 + b], vB0);
      vB1 = fmaf(r, g[2 * 32 + b], vB1);
      vB2 = fmaf(r, g[3 * 32 + b], vB2);
      sC  = fmaf(r, g[4 * 32 + b], sC);
      vD0 = fmaf(r, g[5 * 32 + b], vD0);
      vD1 = fmaf(r, g[6 * 32 + b], vD1);
      vD2 = fmaf(r, g[7 * 32 + b], vD2);
      vE0 = fmaf(r, g[8 * 32 + b], vE0);
      vE1 = fmaf(r, g[9 * 32 + b], vE1);
      vE2 = fmaf(r, g[10 * 32 + b], vE2);
    }
    y0 += sA + vB0 * ux + vB1 * uy + vB2 * uz;
    t0 += sC * ux + vD0 + (vE1 * uz - vE2 * uy);
    t1 += sC * uy + vD1 + (vE2 * ux - vE0 * uz);
    t2 += sC * uz + vD2 + (vE0 * uy - vE1 * ux);
  }
  float4* pb = (float4*)(wso + WS_PB);
  pb[i * 96 + chunk] = make_float4(y0, t0, t1, t2);   // [i][chunk]
}

// ------------------------------------------------------------------
__global__ __launch_bounds__(64) void k_passB2(float* __restrict__ ws, void* out, int it) {
  int i = blockIdx.x * 64 + threadIdx.x;
  int bf = (int)ws[WS_MODE];
  const float4* pb = (const float4*)(ws + WS_PB);
  float ax = 0.f, ay = 0.f, az = 0.f, aw = 0.f;
#pragma unroll 8
  for (int c = 0; c < 96; ++c) {
    float4 v = pb[i * 96 + c];
    ax += v.x; ay += v.y; az += v.z; aw += v.w;
  }
  float y0 = ax + ws[WS_B1L0];
  float sg = expf(y0);
  float s2 = sg * sg;
  float lnrm = 0.5f * logf(6.2831855f * s2);
  const uint32_t* hk = (const uint32_t*)(ws + WS_HKEY);
  uint32_t h0 = hk[it * 2 + 0], h1 = hk[it * 2 + 1];
  float base[3] = {ws[WS_PX + i], ws[WS_PY + i], ws[WS_PZ + i]};
  float tr[3] = {ay, az, aw};
  float logp = 0.0f;
#pragma unroll
  for (int m = 0; m < 3; ++m) {
    float mu = base[m] + tr[m];
    int f = i * 3 + m;
    uint32_t o0, o1;
    tf2x32(h0, h1, 0u, (uint32_t)f, o0, o1);
    uint32_t bits = o0 ^ o1;                     // partitionable 32-bit fold
    float u1 = __uint_as_float((bits >> 9) | 0x3f800000u) - 1.0f;
    const float lo = -0.99999994f;
    float u = fmaxf(lo, u1 * 2.0f + lo);
    float nz = 1.41421354f * erfinv_f(u);
    float oy = mu + nz * sg;
    float d = oy - mu;
    logp -= lnrm + (d * d) / (2.0f * s2);
    if (m == 0) ws[WS_PX + i] = oy;
    else if (m == 1) ws[WS_PY + i] = oy;
    else ws[WS_PZ + i] = oy;
    store_out(out, OUT_YS + (it + 1) * 2304 + i * 3 + m, oy, bf);
    if (it == 1) store_out(out, i * 3 + m, oy, bf);
  }
  ws[WS_LG + it * 768 + i] = logp;
}

// ------------------------------------------------------------------
__global__ void k_logp(float* __restrict__ ws, void* out) {
  __shared__ float red[256];
  int t = threadIdx.x;
  float s = 0.0f;
  for (int e = t; e < 1536; e += 256) s += ws[WS_LG + e];
  red[t] = s;
  __syncthreads();
  for (int off = 128; off; off >>= 1) {
    if (t < off) red[t] += red[t + off];
    __syncthreads();
  }
  if (t == 0) store_out(out, OUT_LOGP, red[0], (int)ws[WS_MODE]);
}

// ------------------------------------------------------------------
extern "C" void kernel_launch(void* const* d_in, const int* in_sizes, int n_in,
                              void* d_out, int out_size, void* d_ws, size_t ws_size,
                              hipStream_t stream) {
  (void)in_sizes; (void)n_in; (void)out_size; (void)ws_size;
  float* ws = (float*)d_ws;
  k_init<<<16, 256, 0, stream>>>(d_in[0], d_in[1], d_in[2], d_in[3], d_in[4], d_in[5],
                                 d_in[6], d_in[7], d_in[8], d_in[9], d_in[10],
                                 d_in[11], d_in[12], d_in[13], d_in[14], d_in[15],
                                 d_in[16], d_in[17], d_in[18], (const int*)d_in[19],
                                 ws, d_out);
  for (int it = 0; it < 2; ++it) {
    k_passA<<<768, 384, 0, stream>>>(ws, ws, it);
    k_passB<<<dim3(96, 3), 256, 0, stream>>>(ws, ws);
    k_passB2<<<12, 64, 0, stream>>>(ws, d_out, it);
  }
  k_logp<<<1, 256, 0, stream>>>(ws, d_out);
}

// Round 9
// 257.808 us; speedup vs baseline: 12.0127x; 12.0127x over previous
//
#include <hip/hip_runtime.h>
#include <hip/hip_bf16.h>
#include <stdint.h>

// ------------------------------------------------------------------
// ws layout (float offsets)
#define WS_MODE  0
#define WS_PX    16        // 768
#define WS_PY    784       // 768
#define WS_PZ    1552      // 768
#define WS_TVEC  2320      // 2*8
#define WS_HKEY  2336      // 4 u32
#define WS_FEATT 2352      // 16*768 transposed [c][j]
#define WS_W0L0  14640     // 24*32
#define WS_B0L0  15408     // 32
#define WS_W0L1  15440     // 24*32
#define WS_W1L0  16208     // 64
#define WS_B1L0  16272     // 1
#define WS_W1L1  16288     // 96*2
#define WS_R00T  16480     // 32*24 natural [b][c]
#define WS_R01T  17248     // 32*24 natural [b][c]
#define WS_R1F   18016     // 5*1024  (R1_00,R1_11d,R1_01,R1_10,R1_11c)
#define WS_GT    23136     // 768*352  G tables [j][comp(11)][b(32)]
#define WS_PB    293472    // 768*96*4 pass-B partials [i][chunk]
#define WS_LG    735840    // 2*768 per-i logp

#define OUT_LOGP 2304
#define OUT_YS   2305

__device__ __forceinline__ float ld_in(const void* p, int idx, int bf) {
  if (bf) return __bfloat162float(((const __hip_bfloat16*)p)[idx]);
  return ((const float*)p)[idx];
}
__device__ __forceinline__ void store_out(void* out, int idx, float v, int bf) {
  if (bf) ((__hip_bfloat16*)out)[idx] = __float2bfloat16(v);
  else ((float*)out)[idx] = v;
}

// JAX threefry2x32 (20 rounds)
__device__ __forceinline__ void tf2x32(uint32_t k0, uint32_t k1, uint32_t x0, uint32_t x1,
                                       uint32_t& o0, uint32_t& o1) {
  uint32_t ks[3] = {k0, k1, k0 ^ k1 ^ 0x1BD11BDAu};
  x0 += ks[0]; x1 += ks[1];
  const int R0[4] = {13, 15, 26, 6};
  const int R1[4] = {17, 29, 16, 24};
#pragma unroll
  for (int i = 0; i < 5; ++i) {
    const int* r = (i & 1) ? R1 : R0;
#pragma unroll
    for (int q = 0; q < 4; ++q) {
      x0 += x1;
      x1 = (x1 << r[q]) | (x1 >> (32 - r[q]));
      x1 ^= x0;
    }
    x0 += ks[(i + 1) % 3];
    x1 += ks[(i + 2) % 3] + (uint32_t)(i + 1);
  }
  o0 = x0; o1 = x1;
}

// XLA ErfInv (f32, Giles)
__device__ __forceinline__ float erfinv_f(float x) {
  float w = -log1pf(-x * x);
  float p;
  if (w < 5.0f) {
    w -= 2.5f;
    p = 2.81022636e-08f;
    p = fmaf(p, w, 3.43273939e-07f);
    p = fmaf(p, w, -3.5233877e-06f);
    p = fmaf(p, w, -4.39150654e-06f);
    p = fmaf(p, w, 0.00021858087f);
    p = fmaf(p, w, -0.00125372503f);
    p = fmaf(p, w, -0.00417768164f);
    p = fmaf(p, w, 0.246640727f);
    p = fmaf(p, w, 1.50140941f);
  } else {
    w = sqrtf(w) - 3.0f;
    p = -0.000200214257f;
    p = fmaf(p, w, 0.000100950558f);
    p = fmaf(p, w, 0.00134934322f);
    p = fmaf(p, w, -0.00367342844f);
    p = fmaf(p, w, 0.00573950773f);
    p = fmaf(p, w, -0.0076224613f);
    p = fmaf(p, w, 0.00943887047f);
    p = fmaf(p, w, 1.00167406f);
    p = fmaf(p, w, 2.83297682f);
  }
  return p * x;
}

// ------------------------------------------------------------------
// dtype probe: every block re-derives bf from the positions buffer (L2-hot).
__device__ int probe_bf(const void* pos, int tid) {
  __shared__ int s_ok;
  if (tid == 0) s_ok = 1;
  __syncthreads();
  const unsigned short* ph = (const unsigned short*)pos;
  int ok = 1;
  for (int e = tid; e < 2304; e += 256) {
    unsigned short v = ph[e];
    if ((v & 0x7fffu) != 0u) {
      int ex = (v >> 7) & 0xff;
      if (ex < 40 || ex > 140) ok = 0;
    }
  }
  if (!ok) atomicAnd(&s_ok, 0);
  __syncthreads();
  return s_ok;
}

// ------------------------------------------------------------------
// k_init: 16 role-based blocks.
__global__ __launch_bounds__(256) void k_init(
    const void* pos, const void* feats, const void* tw1, const void* tb1,
    const void* tw2, const void* tb2, const void* R000, const void* R001,
    const void* W0L0, const void* b0L0, const void* W0L1,
    const void* R100, const void* R111d, const void* R101,
    const void* R110, const void* R111c,
    const void* W1L0, const void* b1L0, const void* W1L1,
    const int* seedp, float* ws, void* out) {
  int tid = threadIdx.x, b = blockIdx.x;
  int bf = probe_bf(pos, tid);
  switch (b) {
    case 0: {  // mode flag + tvec + PRNG
      if (tid == 0) ws[WS_MODE] = (float)bf;
      if (tid < 16) {
        int it = tid >> 3, d = tid & 7;
        float t = (float)(it + 1) * 0.5f;
        float a = ld_in(tb2, d, bf);
        for (int h = 0; h < 32; ++h) {
          float pre = fmaf(t, ld_in(tw1, h, bf), ld_in(tb1, h, bf));
          float th = pre / (1.0f + expf(-pre));
          a = fmaf(th, ld_in(tw2, h * 8 + d, bf), a);
        }
        ws[WS_TVEC + it * 8 + d] = a;
      }
      if (tid == 32) {  // PRNG: partitionable split chain
        uint32_t k0 = 0u, k1 = (uint32_t)seedp[0];
        uint32_t* hk = (uint32_t*)(ws + WS_HKEY);
        uint32_t a0, a1, b0, b1, c0, c1;
        tf2x32(k0, k1, 0u, 0u, a0, a1);
        tf2x32(k0, k1, 0u, 1u, b0, b1);
        hk[0] = b0; hk[1] = b1;
        tf2x32(a0, a1, 0u, 1u, c0, c1);
        hk[2] = c0; hk[3] = c1;
      }
      break;
    }
    case 1: {  // positions SoA
      for (int n = tid; n < 768; n += 256) {
        ws[WS_PX + n] = ld_in(pos, n * 3 + 0, bf);
        ws[WS_PY + n] = ld_in(pos, n * 3 + 1, bf);
        ws[WS_PZ + n] = ld_in(pos, n * 3 + 2, bf);
      }
      break;
    }
    case 2: case 3: {  // out_ys[0] passthrough
      for (int e = (b - 2) * 1152 + tid; e < (b - 1) * 1152; e += 256)
        store_out(out, OUT_YS + e, ld_in(pos, e, bf), bf);
      break;
    }
    case 4: case 5: case 6: case 7:
    case 8: case 9: case 10: case 11: {  // feats transpose, 1536 each
      int base = (b - 4) * 1536;
      for (int e = base + tid; e < base + 1536; e += 256) {
        int j = e >> 4, c = e & 15;
        ws[WS_FEATT + c * 768 + j] = ld_in(feats, e, bf);
      }
      break;
    }
    case 12: {  // layer-0 tables (R0 kept in natural [b][c] layout)
      for (int e = tid; e < 768; e += 256) {
        ws[WS_W0L0 + e] = ld_in(W0L0, e, bf);
        ws[WS_W0L1 + e] = ld_in(W0L1, e, bf);
        ws[WS_R00T + e] = ld_in(R000, e, bf);
        ws[WS_R01T + e] = ld_in(R001, e, bf);
      }
      break;
    }
    case 13: {  // small tables
      if (tid < 32) ws[WS_B0L0 + tid] = ld_in(b0L0, tid, bf);
      if (tid >= 64 && tid < 128) ws[WS_W1L0 + tid - 64] = ld_in(W1L0, tid - 64, bf);
      if (tid >= 128 && tid < 192) {
        for (int e = tid - 128; e < 192; e += 64) ws[WS_W1L1 + e] = ld_in(W1L1, e, bf);
      }
      if (tid == 33) ws[WS_B1L0] = ld_in(b1L0, 0, bf);
      break;
    }
    case 14: case 15: {  // R1 tables, 2560 each
      int base = (b - 14) * 2560;
      const void* tabs[5] = {R100, R111d, R101, R110, R111c};
      for (int e = base + tid; e < base + 2560; e += 256) {
        int tab = e >> 10, off = e & 1023;
        ws[WS_R1F + e] = ld_in(tabs[tab], off, bf);
      }
      break;
    }
  }
}

// ------------------------------------------------------------------
// Pass A v7 (fused, b-outer): one block per i, 512 threads = 2 CH x 4 waves.
// Per lane: 3 j's; per pair, Chebyshev rolls inside the b-loop so no rbf[32]
// array exists; rw0/rw1[12] accumulate per b, fold into out[48] per pair.
__global__ __launch_bounds__(512) void k_passA(const float* __restrict__ ws,
                                               float* __restrict__ wso, int it) {
  int i = blockIdx.x;
  int tid = threadIdx.x;
  int wave = tid >> 6, lane = tid & 63;
  int CH = __builtin_amdgcn_readfirstlane(wave >> 2);   // 0/1, wave-uniform scalar
  int seg = wave & 3;                                   // j sub-segment
  int jbase = seg * 64 + lane;                          // 0..255 within CH group
  float pix = ws[WS_PX + i], piy = ws[WS_PY + i], piz = ws[WS_PZ + i];

  const float* __restrict__ rtt0 = ws + WS_R00T + CH * 12;  // [b][c], stride 24
  const float* __restrict__ rtt1 = ws + WS_R01T + CH * 12;

  float tvv[8];
#pragma unroll
  for (int d = 0; d < 8; ++d) tvv[d] = ws[WS_TVEC + it * 8 + d];

  float out[48];
#pragma unroll
  for (int k = 0; k < 48; ++k) out[k] = 0.0f;

  for (int q = 0; q < 3; ++q) {
    int j = jbase + q * 256;
    float dx = pix - ws[WS_PX + j];
    float dy = piy - ws[WS_PY + j];
    float dz = piz - ws[WS_PZ + j];
    float n2 = dx * dx + dy * dy + dz * dz;
    float nrm = sqrtf(n2 + 1e-8f);
    float invn = 1.0f / nrm;
    float msk = (n2 > 1e-10f) ? invn : 0.0f;
    float ux = dx * invn, uy = dy * invn, uz = dz * invn;
    float sn, cs;
    sincosf(nrm * 0.52359879f, &sn, &cs);
    float twoc = 2.0f * cs;

    float fv[12];
    if (CH == 0) {
#pragma unroll
      for (int c = 0; c < 12; ++c) fv[c] = ws[WS_FEATT + c * 768 + j];
    } else {
#pragma unroll
      for (int c = 0; c < 4; ++c) fv[c] = ws[WS_FEATT + (12 + c) * 768 + j];
#pragma unroll
      for (int c = 4; c < 12; ++c) fv[c] = tvv[c - 4];
    }

    float rw0[12], rw1[12];
#pragma unroll
    for (int c = 0; c < 12; ++c) { rw0[c] = 0.0f; rw1[c] = 0.0f; }
    float sk = sn * msk, skm1 = 0.0f;   // sin(1*t)/safe ; sin(0)=0
#pragma unroll
    for (int b = 0; b < 32; ++b) {
#pragma unroll
      for (int c = 0; c < 12; ++c) {
        rw0[c] = fmaf(sk, rtt0[b * 24 + c], rw0[c]);
        rw1[c] = fmaf(sk, rtt1[b * 24 + c], rw1[c]);
      }
      float s2 = fmaf(twoc, sk, -skm1);   // Chebyshev: sin((b+2)t)/safe
      skm1 = sk; sk = s2;
    }
#pragma unroll
    for (int c = 0; c < 12; ++c) {
      out[c] = fmaf(rw0[c], fv[c], out[c]);
      float pp = rw1[c] * fv[c];
      out[12 + 3 * c + 0] = fmaf(pp, ux, out[12 + 3 * c + 0]);
      out[12 + 3 * c + 1] = fmaf(pp, uy, out[12 + 3 * c + 1]);
      out[12 + 3 * c + 2] = fmaf(pp, uz, out[12 + 3 * c + 2]);
    }
  }

  // 2-step butterfly (4-lane groups), then segment columns into LDS
#pragma unroll
  for (int k = 0; k < 48; ++k) {
    float v = out[k];
    v += __shfl_xor(v, 1);
    v += __shfl_xor(v, 2);
    out[k] = v;
  }
  __shared__ float P[48][129];
  __shared__ float oall[96];
  __shared__ float wf[11][32];
  if ((lane & 3) == 0) {
    int col = wave * 16 + (lane >> 2);   // CH0: 0..63, CH1: 64..127
#pragma unroll
    for (int k = 0; k < 48; ++k) P[k][col] = out[k];
  }
  __syncthreads();
  // reduce 64 cols per (ch, row), store into oall (o0[24] then o1[24][3])
  if (tid < 96) {
    int ch = tid / 48, r = tid % 48;
    float s = 0.0f;
#pragma unroll 8
    for (int c2 = 0; c2 < 64; ++c2) s += P[r][ch * 64 + c2];
    int t;
    if (r < 12) t = ch * 12 + r;
    else { int cc = (r - 12) / 3, m = (r - 12) % 3; t = 24 + 3 * (ch * 12 + cc) + m; }
    oall[t] = s;
  }
  __syncthreads();
  // epilogue: swish/gate + per-h weight folding (h = 0..31)
  if (tid < 32) {
    int h = tid;
    float x0p = ws[WS_B0L0 + h];
#pragma unroll
    for (int c = 0; c < 24; ++c) x0p = fmaf(oall[c], ws[WS_W0L0 + c * 32 + h], x0p);
    float f0b = x0p / (1.0f + expf(-x0p));   // swish
    float v0 = 0.0f, v1 = 0.0f, v2 = 0.0f;
#pragma unroll
    for (int c = 0; c < 24; ++c) {
      float w = ws[WS_W0L1 + c * 32 + h];
      v0 = fmaf(oall[24 + 3 * c + 0], w, v0);
      v1 = fmaf(oall[24 + 3 * c + 1], w, v1);
      v2 = fmaf(oall[24 + 3 * c + 2], w, v2);
    }
    float g = 1.0f / (1.0f + expf(-sqrtf(v0 * v0 + v1 * v1 + v2 * v2 + 1e-8f)));
    float x1m0 = v0 * g, x1m1 = v1 * g, x1m2 = v2 * g;
    float WA = ws[WS_W1L0 + h];
    float WB = ws[WS_W1L0 + 32 + h];
    float Wa = ws[WS_W1L1 + h * 2 + 1];
    float Wb = ws[WS_W1L1 + (32 + h) * 2 + 1];
    float Wc = ws[WS_W1L1 + (64 + h) * 2 + 1];
    wf[0][h] = WA * f0b;
    wf[1][h] = WB * x1m0; wf[2][h] = WB * x1m1; wf[3][h] = WB * x1m2;
    wf[4][h] = Wa * f0b;
    wf[5][h] = Wb * x1m0; wf[6][h] = Wb * x1m1; wf[7][h] = Wb * x1m2;
    wf[8][h] = Wc * x1m0; wf[9][h] = Wc * x1m1; wf[10][h] = Wc * x1m2;
  }
  __syncthreads();
  // layer-1 fold: G[i][comp*32 + b]
  if (tid < 352) {
    int comp = tid >> 5, b = tid & 31;
    int tab = (comp == 0) ? 0 : (comp < 4) ? 1 : (comp == 4) ? 2 : (comp < 8) ? 3 : 4;
    const float* rrow = ws + WS_R1F + tab * 1024 + b * 32;
    float gacc = 0.0f;
#pragma unroll
    for (int c = 0; c < 32; ++c) gacc = fmaf(rrow[c], wf[comp][c], gacc);
    wso[WS_GT + i * 352 + tid] = gacc;
  }
}

// ------------------------------------------------------------------
// Pass B: lanes own i, j uniform per step (scalar G/pos loads).
__global__ __launch_bounds__(256) void k_passB(const float* __restrict__ ws,
                                               float* __restrict__ wso) {
  int i = blockIdx.y * 256 + threadIdx.x;
  int chunk = blockIdx.x;                    // 0..95, 8 j per chunk
  float pix = ws[WS_PX + i], piy = ws[WS_PY + i], piz = ws[WS_PZ + i];
  float y0 = 0.0f, t0 = 0.0f, t1 = 0.0f, t2 = 0.0f;
  for (int q = 0; q < 8; ++q) {
    int j = chunk * 8 + q;
    float dx = pix - ws[WS_PX + j];
    float dy = piy - ws[WS_PY + j];
    float dz = piz - ws[WS_PZ + j];
    float n2 = dx * dx + dy * dy + dz * dz;
    float nrm = sqrtf(n2 + 1e-8f);
    float invn = 1.0f / nrm;
    float msk = (n2 > 1e-10f) ? invn : 0.0f;
    float ux = dx * invn, uy = dy * invn, uz = dz * invn;
    float sn, cs;
    sincosf(nrm * 0.52359879f, &sn, &cs);
    float rbf[32];
    float twoc = 2.0f * cs;
    rbf[0] = sn * msk;
    float skm1 = 0.0f, sk = rbf[0];
#pragma unroll
    for (int k = 1; k < 32; ++k) {
      float s2 = fmaf(twoc, sk, -skm1);
      skm1 = sk; sk = s2; rbf[k] = sk;
    }
    const float* g = ws + WS_GT + j * 352;
    float sA = 0.f, vB0 = 0.f, vB1 = 0.f, vB2 = 0.f, sC = 0.f;
    float vD0 = 0.f, vD1 = 0.f, vD2 = 0.f, vE0 = 0.f, vE1 = 0.f, vE2 = 0.f;
#pragma unroll
    for (int b = 0; b < 32; ++b) {
      float r = rbf[b];
      sA  = fmaf(r, g[0 * 32 + b], sA);
      vB0 = fmaf(r, g[1 * 32 + b], vB0);
      vB1 = fmaf(r, g[2 * 32 + b], vB1);
      vB2 = fmaf(r, g[3 * 32 + b], vB2);
      sC  = fmaf(r, g[4 * 32 + b], sC);
      vD0 = fmaf(r, g[5 * 32 + b], vD0);
      vD1 = fmaf(r, g[6 * 32 + b], vD1);
      vD2 = fmaf(r, g[7 * 32 + b], vD2);
      vE0 = fmaf(r, g[8 * 32 + b], vE0);
      vE1 = fmaf(r, g[9 * 32 + b], vE1);
      vE2 = fmaf(r, g[10 * 32 + b], vE2);
    }
    y0 += sA + vB0 * ux + vB1 * uy + vB2 * uz;
    t0 += sC * ux + vD0 + (vE1 * uz - vE2 * uy);
    t1 += sC * uy + vD1 + (vE2 * ux - vE0 * uz);
    t2 += sC * uz + vD2 + (vE0 * uy - vE1 * ux);
  }
  float4* pb = (float4*)(wso + WS_PB);
  pb[i * 96 + chunk] = make_float4(y0, t0, t1, t2);   // [i][chunk]
}

// ------------------------------------------------------------------
__global__ __launch_bounds__(64) void k_passB2(float* __restrict__ ws, void* out, int it) {
  int i = blockIdx.x * 64 + threadIdx.x;
  int bf = (int)ws[WS_MODE];
  const float4* pb = (const float4*)(ws + WS_PB);
  float ax = 0.f, ay = 0.f, az = 0.f, aw = 0.f;
#pragma unroll 8
  for (int c = 0; c < 96; ++c) {
    float4 v = pb[i * 96 + c];
    ax += v.x; ay += v.y; az += v.z; aw += v.w;
  }
  float y0 = ax + ws[WS_B1L0];
  float sg = expf(y0);
  float s2 = sg * sg;
  float lnrm = 0.5f * logf(6.2831855f * s2);
  const uint32_t* hk = (const uint32_t*)(ws + WS_HKEY);
  uint32_t h0 = hk[it * 2 + 0], h1 = hk[it * 2 + 1];
  float base[3] = {ws[WS_PX + i], ws[WS_PY + i], ws[WS_PZ + i]};
  float tr[3] = {ay, az, aw};
  float logp = 0.0f;
#pragma unroll
  for (int m = 0; m < 3; ++m) {
    float mu = base[m] + tr[m];
    int f = i * 3 + m;
    uint32_t o0, o1;
    tf2x32(h0, h1, 0u, (uint32_t)f, o0, o1);
    uint32_t bits = o0 ^ o1;                     // partitionable 32-bit fold
    float u1 = __uint_as_float((bits >> 9) | 0x3f800000u) - 1.0f;
    const float lo = -0.99999994f;
    float u = fmaxf(lo, u1 * 2.0f + lo);
    float nz = 1.41421354f * erfinv_f(u);
    float oy = mu + nz * sg;
    float d = oy - mu;
    logp -= lnrm + (d * d) / (2.0f * s2);
    if (m == 0) ws[WS_PX + i] = oy;
    else if (m == 1) ws[WS_PY + i] = oy;
    else ws[WS_PZ + i] = oy;
    store_out(out, OUT_YS + (it + 1) * 2304 + i * 3 + m, oy, bf);
    if (it == 1) store_out(out, i * 3 + m, oy, bf);
  }
  ws[WS_LG + it * 768 + i] = logp;
}

// ------------------------------------------------------------------
__global__ void k_logp(float* __restrict__ ws, void* out) {
  __shared__ float red[256];
  int t = threadIdx.x;
  float s = 0.0f;
  for (int e = t; e < 1536; e += 256) s += ws[WS_LG + e];
  red[t] = s;
  __syncthreads();
  for (int off = 128; off; off >>= 1) {
    if (t < off) red[t] += red[t + off];
    __syncthreads();
  }
  if (t == 0) store_out(out, OUT_LOGP, red[0], (int)ws[WS_MODE]);
}

// ------------------------------------------------------------------
extern "C" void kernel_launch(void* const* d_in, const int* in_sizes, int n_in,
                              void* d_out, int out_size, void* d_ws, size_t ws_size,
                              hipStream_t stream) {
  (void)in_sizes; (void)n_in; (void)out_size; (void)ws_size;
  float* ws = (float*)d_ws;
  k_init<<<16, 256, 0, stream>>>(d_in[0], d_in[1], d_in[2], d_in[3], d_in[4], d_in[5],
                                 d_in[6], d_in[7], d_in[8], d_in[9], d_in[10],
                                 d_in[11], d_in[12], d_in[13], d_in[14], d_in[15],
                                 d_in[16], d_in[17], d_in[18], (const int*)d_in[19],
                                 ws, d_out);
  for (int it = 0; it < 2; ++it) {
    k_passA<<<768, 512, 0, stream>>>(ws, ws, it);
    k_passB<<<dim3(96, 3), 256, 0, stream>>>(ws, ws);
    k_passB2<<<12, 64, 0, stream>>>(ws, d_out, it);
  }
  k_logp<<<1, 256, 0, stream>>>(ws, d_out);
}

// Round 11
// 195.291 us; speedup vs baseline: 15.8583x; 1.3201x over previous
//
#include <hip/hip_runtime.h>
#include <hip/hip_bf16.h>
#include <stdint.h>

// ------------------------------------------------------------------
// ws layout (float offsets)
#define WS_MODE  0
#define WS_PX    16        // 768
#define WS_PY    784       // 768
#define WS_PZ    1552      // 768
#define WS_TVEC  2320      // 2*8
#define WS_HKEY  2336      // 4 u32
#define WS_FEATT 2352      // 16*768 transposed [c][j]
#define WS_W0L0  14640     // 24*32
#define WS_B0L0  15408     // 32
#define WS_W0L1  15440     // 24*32
#define WS_W1L0  16208     // 64
#define WS_B1L0  16272     // 1
#define WS_W1L1  16288     // 96*2
#define WS_R00T  16480     // 24*32 transposed [c][b]
#define WS_R01T  17248     // 24*32
#define WS_R1F   18016     // 5*1024  (R1_00,R1_11d,R1_01,R1_10,R1_11c)
#define WS_GT    23136     // 768*352  G tables [j][comp(11)][b(32)]
#define WS_PA    293472    // 6*768*48 pass-A partials [(ch*3+js)][i][48] (aliases PB)
#define WS_PB    293472    // 768*96*4 pass-B partials [i][chunk]
#define WS_LG    735840    // 2*768 per-i logp

#define OUT_LOGP 2304
#define OUT_YS   2305

__device__ __forceinline__ float ld_in(const void* p, int idx, int bf) {
  if (bf) return __bfloat162float(((const __hip_bfloat16*)p)[idx]);
  return ((const float*)p)[idx];
}
__device__ __forceinline__ void store_out(void* out, int idx, float v, int bf) {
  if (bf) ((__hip_bfloat16*)out)[idx] = __float2bfloat16(v);
  else ((float*)out)[idx] = v;
}

// JAX threefry2x32 (20 rounds)
__device__ __forceinline__ void tf2x32(uint32_t k0, uint32_t k1, uint32_t x0, uint32_t x1,
                                       uint32_t& o0, uint32_t& o1) {
  uint32_t ks[3] = {k0, k1, k0 ^ k1 ^ 0x1BD11BDAu};
  x0 += ks[0]; x1 += ks[1];
  const int R0[4] = {13, 15, 26, 6};
  const int R1[4] = {17, 29, 16, 24};
#pragma unroll
  for (int i = 0; i < 5; ++i) {
    const int* r = (i & 1) ? R1 : R0;
#pragma unroll
    for (int q = 0; q < 4; ++q) {
      x0 += x1;
      x1 = (x1 << r[q]) | (x1 >> (32 - r[q]));
      x1 ^= x0;
    }
    x0 += ks[(i + 1) % 3];
    x1 += ks[(i + 2) % 3] + (uint32_t)(i + 1);
  }
  o0 = x0; o1 = x1;
}

// XLA ErfInv (f32, Giles)
__device__ __forceinline__ float erfinv_f(float x) {
  float w = -log1pf(-x * x);
  float p;
  if (w < 5.0f) {
    w -= 2.5f;
    p = 2.81022636e-08f;
    p = fmaf(p, w, 3.43273939e-07f);
    p = fmaf(p, w, -3.5233877e-06f);
    p = fmaf(p, w, -4.39150654e-06f);
    p = fmaf(p, w, 0.00021858087f);
    p = fmaf(p, w, -0.00125372503f);
    p = fmaf(p, w, -0.00417768164f);
    p = fmaf(p, w, 0.246640727f);
    p = fmaf(p, w, 1.50140941f);
  } else {
    w = sqrtf(w) - 3.0f;
    p = -0.000200214257f;
    p = fmaf(p, w, 0.000100950558f);
    p = fmaf(p, w, 0.00134934322f);
    p = fmaf(p, w, -0.00367342844f);
    p = fmaf(p, w, 0.00573950773f);
    p = fmaf(p, w, -0.0076224613f);
    p = fmaf(p, w, 0.00943887047f);
    p = fmaf(p, w, 1.00167406f);
    p = fmaf(p, w, 2.83297682f);
  }
  return p * x;
}

// ------------------------------------------------------------------
// dtype probe: every block re-derives bf from the positions buffer (L2-hot).
__device__ int probe_bf(const void* pos, int tid) {
  __shared__ int s_ok;
  if (tid == 0) s_ok = 1;
  __syncthreads();
  const unsigned short* ph = (const unsigned short*)pos;
  int ok = 1;
  for (int e = tid; e < 2304; e += 256) {
    unsigned short v = ph[e];
    if ((v & 0x7fffu) != 0u) {
      int ex = (v >> 7) & 0xff;
      if (ex < 40 || ex > 140) ok = 0;
    }
  }
  if (!ok) atomicAnd(&s_ok, 0);
  __syncthreads();
  return s_ok;
}

// ------------------------------------------------------------------
// k_init: 16 role-based blocks.
__global__ __launch_bounds__(256) void k_init(
    const void* pos, const void* feats, const void* tw1, const void* tb1,
    const void* tw2, const void* tb2, const void* R000, const void* R001,
    const void* W0L0, const void* b0L0, const void* W0L1,
    const void* R100, const void* R111d, const void* R101,
    const void* R110, const void* R111c,
    const void* W1L0, const void* b1L0, const void* W1L1,
    const int* seedp, float* ws, void* out) {
  int tid = threadIdx.x, b = blockIdx.x;
  int bf = probe_bf(pos, tid);
  switch (b) {
    case 0: {  // mode flag + tvec + PRNG
      if (tid == 0) ws[WS_MODE] = (float)bf;
      if (tid < 16) {
        int it = tid >> 3, d = tid & 7;
        float t = (float)(it + 1) * 0.5f;
        float a = ld_in(tb2, d, bf);
        for (int h = 0; h < 32; ++h) {
          float pre = fmaf(t, ld_in(tw1, h, bf), ld_in(tb1, h, bf));
          float th = pre / (1.0f + expf(-pre));
          a = fmaf(th, ld_in(tw2, h * 8 + d, bf), a);
        }
        ws[WS_TVEC + it * 8 + d] = a;
      }
      if (tid == 32) {  // PRNG: partitionable split chain
        uint32_t k0 = 0u, k1 = (uint32_t)seedp[0];
        uint32_t* hk = (uint32_t*)(ws + WS_HKEY);
        uint32_t a0, a1, b0, b1, c0, c1;
        tf2x32(k0, k1, 0u, 0u, a0, a1);
        tf2x32(k0, k1, 0u, 1u, b0, b1);
        hk[0] = b0; hk[1] = b1;
        tf2x32(a0, a1, 0u, 1u, c0, c1);
        hk[2] = c0; hk[3] = c1;
      }
      break;
    }
    case 1: {  // positions SoA
      for (int n = tid; n < 768; n += 256) {
        ws[WS_PX + n] = ld_in(pos, n * 3 + 0, bf);
        ws[WS_PY + n] = ld_in(pos, n * 3 + 1, bf);
        ws[WS_PZ + n] = ld_in(pos, n * 3 + 2, bf);
      }
      break;
    }
    case 2: case 3: {  // out_ys[0] passthrough
      for (int e = (b - 2) * 1152 + tid; e < (b - 1) * 1152; e += 256)
        store_out(out, OUT_YS + e, ld_in(pos, e, bf), bf);
      break;
    }
    case 4: case 5: case 6: case 7:
    case 8: case 9: case 10: case 11: {  // feats transpose, 1536 each
      int base = (b - 4) * 1536;
      for (int e = base + tid; e < base + 1536; e += 256) {
        int j = e >> 4, c = e & 15;
        ws[WS_FEATT + c * 768 + j] = ld_in(feats, e, bf);
      }
      break;
    }
    case 12: {  // layer-0 tables
      for (int e = tid; e < 768; e += 256) {
        ws[WS_W0L0 + e] = ld_in(W0L0, e, bf);
        ws[WS_W0L1 + e] = ld_in(W0L1, e, bf);
        int bb = e / 24, c = e % 24;
        ws[WS_R00T + c * 32 + bb] = ld_in(R000, e, bf);
        ws[WS_R01T + c * 32 + bb] = ld_in(R001, e, bf);
      }
      break;
    }
    case 13: {  // small tables
      if (tid < 32) ws[WS_B0L0 + tid] = ld_in(b0L0, tid, bf);
      if (tid >= 64 && tid < 128) ws[WS_W1L0 + tid - 64] = ld_in(W1L0, tid - 64, bf);
      if (tid >= 128 && tid < 192) {
        for (int e = tid - 128; e < 192; e += 64) ws[WS_W1L1 + e] = ld_in(W1L1, e, bf);
      }
      if (tid == 33) ws[WS_B1L0] = ld_in(b1L0, 0, bf);
      break;
    }
    case 14: case 15: {  // R1 tables, 2560 each
      int base = (b - 14) * 2560;
      const void* tabs[5] = {R100, R111d, R101, R110, R111c};
      for (int e = base + tid; e < base + 2560; e += 256) {
        int tab = e >> 10, off = e & 1023;
        ws[WS_R1F + e] = ld_in(tabs[tab], off, bf);
      }
      break;
    }
  }
}

// ------------------------------------------------------------------
// Pass A v5: grid (768 i, 3 jset, 2 CH); block 256 = one j per lane.
// CH is block-uniform; both branches are straight-line (round-5 body).
__global__ __launch_bounds__(256) void k_passA(const float* __restrict__ ws,
                                               float* __restrict__ wso, int it) {
  int i = blockIdx.x, jset = blockIdx.y, CH = blockIdx.z;
  int tid = threadIdx.x, lane = tid & 63, w = tid >> 6;
  int j = jset * 256 + tid;
  float pix = ws[WS_PX + i], piy = ws[WS_PY + i], piz = ws[WS_PZ + i];

  float dx = pix - ws[WS_PX + j];
  float dy = piy - ws[WS_PY + j];
  float dz = piz - ws[WS_PZ + j];
  float n2 = dx * dx + dy * dy + dz * dz;
  float nrm = sqrtf(n2 + 1e-8f);
  float invn = 1.0f / nrm;
  float msk = (n2 > 1e-10f) ? invn : 0.0f;
  float ux = dx * invn, uy = dy * invn, uz = dz * invn;
  float sn, cs;
  sincosf(nrm * 0.52359879f, &sn, &cs);
  float rbf[32];
  float twoc = 2.0f * cs;
  rbf[0] = sn * msk;
  float skm1 = 0.0f, sk = rbf[0];
#pragma unroll
  for (int k = 1; k < 32; ++k) {       // sin(k*theta)/safe via Chebyshev
    float s2 = fmaf(twoc, sk, -skm1);
    skm1 = sk; sk = s2; rbf[k] = sk;
  }

  float fv[12];
  const float* __restrict__ rt0;
  const float* __restrict__ rt1;
  if (CH == 0) {
    rt0 = ws + WS_R00T; rt1 = ws + WS_R01T;
#pragma unroll
    for (int c = 0; c < 12; ++c) fv[c] = ws[WS_FEATT + c * 768 + j];
  } else {
    rt0 = ws + WS_R00T + 384; rt1 = ws + WS_R01T + 384;
#pragma unroll
    for (int c = 0; c < 4; ++c) fv[c] = ws[WS_FEATT + (12 + c) * 768 + j];
#pragma unroll
    for (int c = 4; c < 12; ++c) fv[c] = ws[WS_TVEC + it * 8 + (c - 4)];
  }

  float out[48];
#pragma unroll
  for (int c = 0; c < 12; ++c) {
    float rw0 = 0.0f, rw1 = 0.0f;
#pragma unroll
    for (int bq = 0; bq < 32; ++bq) {
      rw0 = fmaf(rbf[bq], rt0[c * 32 + bq], rw0);
      rw1 = fmaf(rbf[bq], rt1[c * 32 + bq], rw1);
    }
    float f = fv[c];
    out[c] = rw0 * f;
    float pp = rw1 * f;
    out[12 + 3 * c + 0] = pp * ux;
    out[12 + 3 * c + 1] = pp * uy;
    out[12 + 3 * c + 2] = pp * uz;
  }

  // 2-step butterfly (4-lane groups), then LDS reduce over 64 cols
#pragma unroll
  for (int k = 0; k < 48; ++k) {
    float v = out[k];
    v += __shfl_xor(v, 1);
    v += __shfl_xor(v, 2);
    out[k] = v;
  }
  __shared__ float P[48][65];
  if ((lane & 3) == 0) {
    int col = w * 16 + (lane >> 2);
#pragma unroll
    for (int k = 0; k < 48; ++k) P[k][col] = out[k];
  }
  __syncthreads();
  if (tid < 48) {
    float s = 0.0f;
#pragma unroll 8
    for (int q = 0; q < 64; ++q) s += P[tid][q];
    wso[WS_PA + ((CH * 3 + jset) * 768 + i) * 48 + tid] = s;
  }
}

// ------------------------------------------------------------------
// Pass A epilogue per i: assemble o0/o1 from 6 partial segments,
// x0 (swish), x1 (gated), fold layer-1 weights into G[comp][b].
__global__ __launch_bounds__(64) void k_passA2(const float* __restrict__ ws,
                                               float* __restrict__ wso) {
  int i = blockIdx.x, lane = threadIdx.x;
  __shared__ float oall[96];
  __shared__ float wf[11][32];
  // gather: t<24 -> o0[c=t]; t>=24 -> o1[c=(t-24)/3][m=(t-24)%3]
#pragma unroll
  for (int rep = 0; rep < 2; ++rep) {
    int t = rep * 64 + lane;
    if (rep == 0 || lane < 32) {
      int ch, k;
      if (t < 24) { ch = t / 12; k = t % 12; }
      else { int u = t - 24; int c = u / 3, m = u % 3; ch = c / 12; k = 12 + 3 * (c % 12) + m; }
      float s = 0.0f;
#pragma unroll
      for (int js = 0; js < 3; ++js)
        s += ws[WS_PA + ((ch * 3 + js) * 768 + i) * 48 + k];
      oall[t] = s;
    }
  }
  __syncthreads();
  if (lane < 32) {
    int h = lane;
    float x0p = ws[WS_B0L0 + h];
#pragma unroll
    for (int c = 0; c < 24; ++c) x0p = fmaf(oall[c], ws[WS_W0L0 + c * 32 + h], x0p);
    float f0b = x0p / (1.0f + expf(-x0p));   // swish
    float v0 = 0.0f, v1 = 0.0f, v2 = 0.0f;
#pragma unroll
    for (int c = 0; c < 24; ++c) {
      float w = ws[WS_W0L1 + c * 32 + h];
      v0 = fmaf(oall[24 + 3 * c + 0], w, v0);
      v1 = fmaf(oall[24 + 3 * c + 1], w, v1);
      v2 = fmaf(oall[24 + 3 * c + 2], w, v2);
    }
    float g = 1.0f / (1.0f + expf(-sqrtf(v0 * v0 + v1 * v1 + v2 * v2 + 1e-8f)));
    float x1m0 = v0 * g, x1m1 = v1 * g, x1m2 = v2 * g;
    float WA = ws[WS_W1L0 + h];
    float WB = ws[WS_W1L0 + 32 + h];
    float Wa = ws[WS_W1L1 + h * 2 + 1];
    float Wb = ws[WS_W1L1 + (32 + h) * 2 + 1];
    float Wc = ws[WS_W1L1 + (64 + h) * 2 + 1];
    wf[0][h] = WA * f0b;
    wf[1][h] = WB * x1m0; wf[2][h] = WB * x1m1; wf[3][h] = WB * x1m2;
    wf[4][h] = Wa * f0b;
    wf[5][h] = Wb * x1m0; wf[6][h] = Wb * x1m1; wf[7][h] = Wb * x1m2;
    wf[8][h] = Wc * x1m0; wf[9][h] = Wc * x1m1; wf[10][h] = Wc * x1m2;
  }
  __syncthreads();
  for (int tt = lane; tt < 352; tt += 64) {
    int comp = tt >> 5, b = tt & 31;
    int tab = (comp == 0) ? 0 : (comp < 4) ? 1 : (comp == 4) ? 2 : (comp < 8) ? 3 : 4;
    const float* rrow = ws + WS_R1F + tab * 1024 + b * 32;
    float gacc = 0.0f;
#pragma unroll
    for (int c = 0; c < 32; ++c) gacc = fmaf(rrow[c], wf[comp][c], gacc);
    wso[WS_GT + i * 352 + tt] = gacc;
  }
}

// ------------------------------------------------------------------
// Pass B: lanes own i, j uniform per step (scalar G/pos loads).
__global__ __launch_bounds__(256) void k_passB(const float* __restrict__ ws,
                                               float* __restrict__ wso) {
  int i = blockIdx.y * 256 + threadIdx.x;
  int chunk = blockIdx.x;                    // 0..95, 8 j per chunk
  float pix = ws[WS_PX + i], piy = ws[WS_PY + i], piz = ws[WS_PZ + i];
  float y0 = 0.0f, t0 = 0.0f, t1 = 0.0f, t2 = 0.0f;
  for (int q = 0; q < 8; ++q) {
    int j = chunk * 8 + q;
    float dx = pix - ws[WS_PX + j];
    float dy = piy - ws[WS_PY + j];
    float dz = piz - ws[WS_PZ + j];
    float n2 = dx * dx + dy * dy + dz * dz;
    float nrm = sqrtf(n2 + 1e-8f);
    float invn = 1.0f / nrm;
    float msk = (n2 > 1e-10f) ? invn : 0.0f;
    float ux = dx * invn, uy = dy * invn, uz = dz * invn;
    float sn, cs;
    sincosf(nrm * 0.52359879f, &sn, &cs);
    float rbf[32];
    float twoc = 2.0f * cs;
    rbf[0] = sn * msk;
    float skm1 = 0.0f, sk = rbf[0];
#pragma unroll
    for (int k = 1; k < 32; ++k) {
      float s2 = fmaf(twoc, sk, -skm1);
      skm1 = sk; sk = s2; rbf[k] = sk;
    }
    const float* g = ws + WS_GT + j * 352;
    float sA = 0.f, vB0 = 0.f, vB1 = 0.f, vB2 = 0.f, sC = 0.f;
    float vD0 = 0.f, vD1 = 0.f, vD2 = 0.f, vE0 = 0.f, vE1 = 0.f, vE2 = 0.f;
#pragma unroll
    for (int b = 0; b < 32; ++b) {
      float r = rbf[b];
      sA  = fmaf(r, g[0 * 32 + b], sA);
      vB0 = fmaf(r, g[1 * 32 + b], vB0);
      vB1 = fmaf(r, g[2 * 32 + b], vB1);
      vB2 = fmaf(r, g[3 * 32 + b], vB2);
      sC  = fmaf(r, g[4 * 32 + b], sC);
      vD0 = fmaf(r, g[5 * 32 + b], vD0);
      vD1 = fmaf(r, g[6 * 32 + b], vD1);
      vD2 = fmaf(r, g[7 * 32 + b], vD2);
      vE0 = fmaf(r, g[8 * 32 + b], vE0);
      vE1 = fmaf(r, g[9 * 32 + b], vE1);
      vE2 = fmaf(r, g[10 * 32 + b], vE2);
    }
    y0 += sA + vB0 * ux + vB1 * uy + vB2 * uz;
    t0 += sC * ux + vD0 + (vE1 * uz - vE2 * uy);
    t1 += sC * uy + vD1 + (vE2 * ux - vE0 * uz);
    t2 += sC * uz + vD2 + (vE0 * uy - vE1 * ux);
  }
  float4* pb = (float4*)(wso + WS_PB);
  pb[i * 96 + chunk] = make_float4(y0, t0, t1, t2);   // [i][chunk]
}

// ------------------------------------------------------------------
__global__ __launch_bounds__(64) void k_passB2(float* __restrict__ ws, void* out, int it) {
  int i = blockIdx.x * 64 + threadIdx.x;
  int bf = (int)ws[WS_MODE];
  const float4* pb = (const float4*)(ws + WS_PB);
  float ax = 0.f, ay = 0.f, az = 0.f, aw = 0.f;
#pragma unroll 8
  for (int c = 0; c < 96; ++c) {
    float4 v = pb[i * 96 + c];
    ax += v.x; ay += v.y; az += v.z; aw += v.w;
  }
  float y0 = ax + ws[WS_B1L0];
  float sg = expf(y0);
  float s2 = sg * sg;
  float lnrm = 0.5f * logf(6.2831855f * s2);
  const uint32_t* hk = (const uint32_t*)(ws + WS_HKEY);
  uint32_t h0 = hk[it * 2 + 0], h1 = hk[it * 2 + 1];
  float base[3] = {ws[WS_PX + i], ws[WS_PY + i], ws[WS_PZ + i]};
  float tr[3] = {ay, az, aw};
  float logp = 0.0f;
#pragma unroll
  for (int m = 0; m < 3; ++m) {
    float mu = base[m] + tr[m];
    int f = i * 3 + m;
    uint32_t o0, o1;
    tf2x32(h0, h1, 0u, (uint32_t)f, o0, o1);
    uint32_t bits = o0 ^ o1;                     // partitionable 32-bit fold
    float u1 = __uint_as_float((bits >> 9) | 0x3f800000u) - 1.0f;
    const float lo = -0.99999994f;
    float u = fmaxf(lo, u1 * 2.0f + lo);
    float nz = 1.41421354f * erfinv_f(u);
    float oy = mu + nz * sg;
    float d = oy - mu;
    logp -= lnrm + (d * d) / (2.0f * s2);
    if (m == 0) ws[WS_PX + i] = oy;
    else if (m == 1) ws[WS_PY + i] = oy;
    else ws[WS_PZ + i] = oy;
    store_out(out, OUT_YS + (it + 1) * 2304 + i * 3 + m, oy, bf);
    if (it == 1) store_out(out, i * 3 + m, oy, bf);
  }
  ws[WS_LG + it * 768 + i] = logp;
}

// ------------------------------------------------------------------
__global__ void k_logp(float* __restrict__ ws, void* out) {
  __shared__ float red[256];
  int t = threadIdx.x;
  float s = 0.0f;
  for (int e = t; e < 1536; e += 256) s += ws[WS_LG + e];
  red[t] = s;
  __syncthreads();
  for (int off = 128; off; off >>= 1) {
    if (t < off) red[t] += red[t + off];
    __syncthreads();
  }
  if (t == 0) store_out(out, OUT_LOGP, red[0], (int)ws[WS_MODE]);
}

// ------------------------------------------------------------------
extern "C" void kernel_launch(void* const* d_in, const int* in_sizes, int n_in,
                              void* d_out, int out_size, void* d_ws, size_t ws_size,
                              hipStream_t stream) {
  (void)in_sizes; (void)n_in; (void)out_size; (void)ws_size;
  float* ws = (float*)d_ws;
  k_init<<<16, 256, 0, stream>>>(d_in[0], d_in[1], d_in[2], d_in[3], d_in[4], d_in[5],
                                 d_in[6], d_in[7], d_in[8], d_in[9], d_in[10],
                                 d_in[11], d_in[12], d_in[13], d_in[14], d_in[15],
                                 d_in[16], d_in[17], d_in[18], (const int*)d_in[19],
                                 ws, d_out);
  for (int it = 0; it < 2; ++it) {
    k_passA<<<dim3(768, 3, 2), 256, 0, stream>>>(ws, ws, it);
    k_passA2<<<768, 64, 0, stream>>>(ws, ws);
    k_passB<<<dim3(96, 3), 256, 0, stream>>>(ws, ws);
    k_passB2<<<12, 64, 0, stream>>>(ws, d_out, it);
  }
  k_logp<<<1, 256, 0, stream>>>(ws, d_out);
}

// Round 12
// 189.450 us; speedup vs baseline: 16.3472x; 1.0308x over previous
//
#include <hip/hip_runtime.h>
#include <hip/hip_bf16.h>
#include <stdint.h>

// ------------------------------------------------------------------
// ws layout (float offsets)
#define WS_MODE  0
#define WS_PX    16        // 768
#define WS_PY    784       // 768
#define WS_PZ    1552      // 768
#define WS_TVEC  2320      // 2*8
#define WS_HKEY  2336      // 4 u32
#define WS_FEATT 2352      // 16*768 transposed [c][j]
#define WS_W0L0  14640     // 24*32
#define WS_B0L0  15408     // 32
#define WS_W0L1  15440     // 24*32
#define WS_W1L0  16208     // 64
#define WS_B1L0  16272     // 1
#define WS_W1L1  16288     // 96*2
#define WS_R00T  16480     // 32*24 natural [b][c]
#define WS_R01T  17248     // 32*24 natural [b][c]
#define WS_R1F   18016     // 5*1024  (R1_00,R1_11d,R1_01,R1_10,R1_11c)
#define WS_GT    23136     // 768*352  G tables [j][comp(11)][b(32)]
#define WS_PA    293472    // 6*768*48 pass-A partials [(ch*3+js)][i][48] (aliases PB)
#define WS_PB    293472    // 768*96*4 pass-B partials [i][chunk]
#define WS_LG    735840    // 2*768 per-i logp

#define OUT_LOGP 2304
#define OUT_YS   2305

__device__ __forceinline__ float ld_in(const void* p, int idx, int bf) {
  if (bf) return __bfloat162float(((const __hip_bfloat16*)p)[idx]);
  return ((const float*)p)[idx];
}
__device__ __forceinline__ void store_out(void* out, int idx, float v, int bf) {
  if (bf) ((__hip_bfloat16*)out)[idx] = __float2bfloat16(v);
  else ((float*)out)[idx] = v;
}

// JAX threefry2x32 (20 rounds)
__device__ __forceinline__ void tf2x32(uint32_t k0, uint32_t k1, uint32_t x0, uint32_t x1,
                                       uint32_t& o0, uint32_t& o1) {
  uint32_t ks[3] = {k0, k1, k0 ^ k1 ^ 0x1BD11BDAu};
  x0 += ks[0]; x1 += ks[1];
  const int R0[4] = {13, 15, 26, 6};
  const int R1[4] = {17, 29, 16, 24};
#pragma unroll
  for (int i = 0; i < 5; ++i) {
    const int* r = (i & 1) ? R1 : R0;
#pragma unroll
    for (int q = 0; q < 4; ++q) {
      x0 += x1;
      x1 = (x1 << r[q]) | (x1 >> (32 - r[q]));
      x1 ^= x0;
    }
    x0 += ks[(i + 1) % 3];
    x1 += ks[(i + 2) % 3] + (uint32_t)(i + 1);
  }
  o0 = x0; o1 = x1;
}

// XLA ErfInv (f32, Giles)
__device__ __forceinline__ float erfinv_f(float x) {
  float w = -log1pf(-x * x);
  float p;
  if (w < 5.0f) {
    w -= 2.5f;
    p = 2.81022636e-08f;
    p = fmaf(p, w, 3.43273939e-07f);
    p = fmaf(p, w, -3.5233877e-06f);
    p = fmaf(p, w, -4.39150654e-06f);
    p = fmaf(p, w, 0.00021858087f);
    p = fmaf(p, w, -0.00125372503f);
    p = fmaf(p, w, -0.00417768164f);
    p = fmaf(p, w, 0.246640727f);
    p = fmaf(p, w, 1.50140941f);
  } else {
    w = sqrtf(w) - 3.0f;
    p = -0.000200214257f;
    p = fmaf(p, w, 0.000100950558f);
    p = fmaf(p, w, 0.00134934322f);
    p = fmaf(p, w, -0.00367342844f);
    p = fmaf(p, w, 0.00573950773f);
    p = fmaf(p, w, -0.0076224613f);
    p = fmaf(p, w, 0.00943887047f);
    p = fmaf(p, w, 1.00167406f);
    p = fmaf(p, w, 2.83297682f);
  }
  return p * x;
}

// ------------------------------------------------------------------
// dtype probe: every block re-derives bf from the positions buffer (L2-hot).
__device__ int probe_bf(const void* pos, int tid) {
  __shared__ int s_ok;
  if (tid == 0) s_ok = 1;
  __syncthreads();
  const unsigned short* ph = (const unsigned short*)pos;
  int ok = 1;
  for (int e = tid; e < 2304; e += 256) {
    unsigned short v = ph[e];
    if ((v & 0x7fffu) != 0u) {
      int ex = (v >> 7) & 0xff;
      if (ex < 40 || ex > 140) ok = 0;
    }
  }
  if (!ok) atomicAnd(&s_ok, 0);
  __syncthreads();
  return s_ok;
}

// ------------------------------------------------------------------
// k_init: 16 role-based blocks.
__global__ __launch_bounds__(256) void k_init(
    const void* pos, const void* feats, const void* tw1, const void* tb1,
    const void* tw2, const void* tb2, const void* R000, const void* R001,
    const void* W0L0, const void* b0L0, const void* W0L1,
    const void* R100, const void* R111d, const void* R101,
    const void* R110, const void* R111c,
    const void* W1L0, const void* b1L0, const void* W1L1,
    const int* seedp, float* ws, void* out) {
  int tid = threadIdx.x, b = blockIdx.x;
  int bf = probe_bf(pos, tid);
  switch (b) {
    case 0: {  // mode flag + tvec + PRNG
      if (tid == 0) ws[WS_MODE] = (float)bf;
      if (tid < 16) {
        int it = tid >> 3, d = tid & 7;
        float t = (float)(it + 1) * 0.5f;
        float a = ld_in(tb2, d, bf);
        for (int h = 0; h < 32; ++h) {
          float pre = fmaf(t, ld_in(tw1, h, bf), ld_in(tb1, h, bf));
          float th = pre / (1.0f + expf(-pre));
          a = fmaf(th, ld_in(tw2, h * 8 + d, bf), a);
        }
        ws[WS_TVEC + it * 8 + d] = a;
      }
      if (tid == 32) {  // PRNG: partitionable split chain
        uint32_t k0 = 0u, k1 = (uint32_t)seedp[0];
        uint32_t* hk = (uint32_t*)(ws + WS_HKEY);
        uint32_t a0, a1, b0, b1, c0, c1;
        tf2x32(k0, k1, 0u, 0u, a0, a1);
        tf2x32(k0, k1, 0u, 1u, b0, b1);
        hk[0] = b0; hk[1] = b1;
        tf2x32(a0, a1, 0u, 1u, c0, c1);
        hk[2] = c0; hk[3] = c1;
      }
      break;
    }
    case 1: {  // positions SoA
      for (int n = tid; n < 768; n += 256) {
        ws[WS_PX + n] = ld_in(pos, n * 3 + 0, bf);
        ws[WS_PY + n] = ld_in(pos, n * 3 + 1, bf);
        ws[WS_PZ + n] = ld_in(pos, n * 3 + 2, bf);
      }
      break;
    }
    case 2: case 3: {  // out_ys[0] passthrough
      for (int e = (b - 2) * 1152 + tid; e < (b - 1) * 1152; e += 256)
        store_out(out, OUT_YS + e, ld_in(pos, e, bf), bf);
      break;
    }
    case 4: case 5: case 6: case 7:
    case 8: case 9: case 10: case 11: {  // feats transpose, 1536 each
      int base = (b - 4) * 1536;
      for (int e = base + tid; e < base + 1536; e += 256) {
        int j = e >> 4, c = e & 15;
        ws[WS_FEATT + c * 768 + j] = ld_in(feats, e, bf);
      }
      break;
    }
    case 12: {  // layer-0 tables; R0 in natural [b][c] layout
      for (int e = tid; e < 768; e += 256) {
        ws[WS_W0L0 + e] = ld_in(W0L0, e, bf);
        ws[WS_W0L1 + e] = ld_in(W0L1, e, bf);
        ws[WS_R00T + e] = ld_in(R000, e, bf);
        ws[WS_R01T + e] = ld_in(R001, e, bf);
      }
      break;
    }
    case 13: {  // small tables
      if (tid < 32) ws[WS_B0L0 + tid] = ld_in(b0L0, tid, bf);
      if (tid >= 64 && tid < 128) ws[WS_W1L0 + tid - 64] = ld_in(W1L0, tid - 64, bf);
      if (tid >= 128 && tid < 192) {
        for (int e = tid - 128; e < 192; e += 64) ws[WS_W1L1 + e] = ld_in(W1L1, e, bf);
      }
      if (tid == 33) ws[WS_B1L0] = ld_in(b1L0, 0, bf);
      break;
    }
    case 14: case 15: {  // R1 tables, 2560 each
      int base = (b - 14) * 2560;
      const void* tabs[5] = {R100, R111d, R101, R110, R111c};
      for (int e = base + tid; e < base + 2560; e += 256) {
        int tab = e >> 10, off = e & 1023;
        ws[WS_R1F + e] = ld_in(tabs[tab], off, bf);
      }
      break;
    }
  }
}

// ------------------------------------------------------------------
// Pass A v8: grid (768 i, 3 jset, 2 CH); block 256 = one j per lane.
// b-OUTER contraction: tables in natural [b][c] layout -> wave-uniform
// contiguous rows -> scalar loads; Chebyshev rolls in 2 regs (no rbf[32]).
__global__ __launch_bounds__(256) void k_passA(const float* __restrict__ ws,
                                               float* __restrict__ wso, int it) {
  int i = blockIdx.x, jset = blockIdx.y, CH = blockIdx.z;
  int tid = threadIdx.x, lane = tid & 63, w = tid >> 6;
  int j = jset * 256 + tid;
  float pix = ws[WS_PX + i], piy = ws[WS_PY + i], piz = ws[WS_PZ + i];

  float dx = pix - ws[WS_PX + j];
  float dy = piy - ws[WS_PY + j];
  float dz = piz - ws[WS_PZ + j];
  float n2 = dx * dx + dy * dy + dz * dz;
  float nrm = sqrtf(n2 + 1e-8f);
  float invn = 1.0f / nrm;
  float msk = (n2 > 1e-10f) ? invn : 0.0f;
  float ux = dx * invn, uy = dy * invn, uz = dz * invn;
  float sn, cs;
  sincosf(nrm * 0.52359879f, &sn, &cs);
  float twoc = 2.0f * cs;

  float fv[12];
  const float* __restrict__ rt0 = ws + WS_R00T + CH * 12;  // [b][c] rows of 24
  const float* __restrict__ rt1 = ws + WS_R01T + CH * 12;
  if (CH == 0) {
#pragma unroll
    for (int c = 0; c < 12; ++c) fv[c] = ws[WS_FEATT + c * 768 + j];
  } else {
#pragma unroll
    for (int c = 0; c < 4; ++c) fv[c] = ws[WS_FEATT + (12 + c) * 768 + j];
#pragma unroll
    for (int c = 4; c < 12; ++c) fv[c] = ws[WS_TVEC + it * 8 + (c - 4)];
  }

  float rw0[12], rw1[12];
#pragma unroll
  for (int c = 0; c < 12; ++c) { rw0[c] = 0.0f; rw1[c] = 0.0f; }
  float sk = sn * msk, skm1 = 0.0f;   // sin(1*t)/safe ; sin(0)=0
#pragma unroll
  for (int b = 0; b < 32; ++b) {
#pragma unroll
    for (int c = 0; c < 12; ++c) {
      rw0[c] = fmaf(sk, rt0[b * 24 + c], rw0[c]);
      rw1[c] = fmaf(sk, rt1[b * 24 + c], rw1[c]);
    }
    float s2 = fmaf(twoc, sk, -skm1);   // Chebyshev: sin((b+2)t)/safe
    skm1 = sk; sk = s2;
  }

  float out[48];
#pragma unroll
  for (int c = 0; c < 12; ++c) {
    float f = fv[c];
    out[c] = rw0[c] * f;
    float pp = rw1[c] * f;
    out[12 + 3 * c + 0] = pp * ux;
    out[12 + 3 * c + 1] = pp * uy;
    out[12 + 3 * c + 2] = pp * uz;
  }

  // 2-step butterfly (4-lane groups), then LDS reduce over 64 cols
#pragma unroll
  for (int k = 0; k < 48; ++k) {
    float v = out[k];
    v += __shfl_xor(v, 1);
    v += __shfl_xor(v, 2);
    out[k] = v;
  }
  __shared__ float P[48][65];
  if ((lane & 3) == 0) {
    int col = w * 16 + (lane >> 2);
#pragma unroll
    for (int k = 0; k < 48; ++k) P[k][col] = out[k];
  }
  __syncthreads();
  if (tid < 48) {
    float s = 0.0f;
#pragma unroll 8
    for (int q = 0; q < 64; ++q) s += P[tid][q];
    wso[WS_PA + ((CH * 3 + jset) * 768 + i) * 48 + tid] = s;
  }
}

// ------------------------------------------------------------------
// Pass A epilogue per i: assemble o0/o1 from 6 partial segments,
// x0 (swish), x1 (gated), fold layer-1 weights into G[comp][b].
__global__ __launch_bounds__(64) void k_passA2(const float* __restrict__ ws,
                                               float* __restrict__ wso) {
  int i = blockIdx.x, lane = threadIdx.x;
  __shared__ float oall[96];
  __shared__ float wf[11][32];
  // gather: t<24 -> o0[c=t]; t>=24 -> o1[c=(t-24)/3][m=(t-24)%3]
#pragma unroll
  for (int rep = 0; rep < 2; ++rep) {
    int t = rep * 64 + lane;
    if (rep == 0 || lane < 32) {
      int ch, k;
      if (t < 24) { ch = t / 12; k = t % 12; }
      else { int u = t - 24; int c = u / 3, m = u % 3; ch = c / 12; k = 12 + 3 * (c % 12) + m; }
      float s = 0.0f;
#pragma unroll
      for (int js = 0; js < 3; ++js)
        s += ws[WS_PA + ((ch * 3 + js) * 768 + i) * 48 + k];
      oall[t] = s;
    }
  }
  __syncthreads();
  if (lane < 32) {
    int h = lane;
    float x0p = ws[WS_B0L0 + h];
#pragma unroll
    for (int c = 0; c < 24; ++c) x0p = fmaf(oall[c], ws[WS_W0L0 + c * 32 + h], x0p);
    float f0b = x0p / (1.0f + expf(-x0p));   // swish
    float v0 = 0.0f, v1 = 0.0f, v2 = 0.0f;
#pragma unroll
    for (int c = 0; c < 24; ++c) {
      float w = ws[WS_W0L1 + c * 32 + h];
      v0 = fmaf(oall[24 + 3 * c + 0], w, v0);
      v1 = fmaf(oall[24 + 3 * c + 1], w, v1);
      v2 = fmaf(oall[24 + 3 * c + 2], w, v2);
    }
    float g = 1.0f / (1.0f + expf(-sqrtf(v0 * v0 + v1 * v1 + v2 * v2 + 1e-8f)));
    float x1m0 = v0 * g, x1m1 = v1 * g, x1m2 = v2 * g;
    float WA = ws[WS_W1L0 + h];
    float WB = ws[WS_W1L0 + 32 + h];
    float Wa = ws[WS_W1L1 + h * 2 + 1];
    float Wb = ws[WS_W1L1 + (32 + h) * 2 + 1];
    float Wc = ws[WS_W1L1 + (64 + h) * 2 + 1];
    wf[0][h] = WA * f0b;
    wf[1][h] = WB * x1m0; wf[2][h] = WB * x1m1; wf[3][h] = WB * x1m2;
    wf[4][h] = Wa * f0b;
    wf[5][h] = Wb * x1m0; wf[6][h] = Wb * x1m1; wf[7][h] = Wb * x1m2;
    wf[8][h] = Wc * x1m0; wf[9][h] = Wc * x1m1; wf[10][h] = Wc * x1m2;
  }
  __syncthreads();
  for (int tt = lane; tt < 352; tt += 64) {
    int comp = tt >> 5, b = tt & 31;
    int tab = (comp == 0) ? 0 : (comp < 4) ? 1 : (comp == 4) ? 2 : (comp < 8) ? 3 : 4;
    const float* rrow = ws + WS_R1F + tab * 1024 + b * 32;
    float gacc = 0.0f;
#pragma unroll
    for (int c = 0; c < 32; ++c) gacc = fmaf(rrow[c], wf[comp][c], gacc);
    wso[WS_GT + i * 352 + tt] = gacc;
  }
}

// ------------------------------------------------------------------
// Pass B: 64-thread blocks (1 wave), grid (96 chunks, 12 i-groups).
__global__ __launch_bounds__(64) void k_passB(const float* __restrict__ ws,
                                              float* __restrict__ wso) {
  int i = blockIdx.y * 64 + threadIdx.x;
  int chunk = blockIdx.x;                    // 0..95, 8 j per chunk
  float pix = ws[WS_PX + i], piy = ws[WS_PY + i], piz = ws[WS_PZ + i];
  float y0 = 0.0f, t0 = 0.0f, t1 = 0.0f, t2 = 0.0f;
  for (int q = 0; q < 8; ++q) {
    int j = chunk * 8 + q;
    float dx = pix - ws[WS_PX + j];
    float dy = piy - ws[WS_PY + j];
    float dz = piz - ws[WS_PZ + j];
    float n2 = dx * dx + dy * dy + dz * dz;
    float nrm = sqrtf(n2 + 1e-8f);
    float invn = 1.0f / nrm;
    float msk = (n2 > 1e-10f) ? invn : 0.0f;
    float ux = dx * invn, uy = dy * invn, uz = dz * invn;
    float sn, cs;
    sincosf(nrm * 0.52359879f, &sn, &cs);
    float rbf[32];
    float twoc = 2.0f * cs;
    rbf[0] = sn * msk;
    float skm1 = 0.0f, sk = rbf[0];
#pragma unroll
    for (int k = 1; k < 32; ++k) {
      float s2 = fmaf(twoc, sk, -skm1);
      skm1 = sk; sk = s2; rbf[k] = sk;
    }
    const float* g = ws + WS_GT + j * 352;
    float sA = 0.f, vB0 = 0.f, vB1 = 0.f, vB2 = 0.f, sC = 0.f;
    float vD0 = 0.f, vD1 = 0.f, vD2 = 0.f, vE0 = 0.f, vE1 = 0.f, vE2 = 0.f;
#pragma unroll
    for (int b = 0; b < 32; ++b) {
      float r = rbf[b];
      sA  = fmaf(r, g[0 * 32 + b], sA);
      vB0 = fmaf(r, g[1 * 32 + b], vB0);
      vB1 = fmaf(r, g[2 * 32 + b], vB1);
      vB2 = fmaf(r, g[3 * 32 + b], vB2);
      sC  = fmaf(r, g[4 * 32 + b], sC);
      vD0 = fmaf(r, g[5 * 32 + b], vD0);
      vD1 = fmaf(r, g[6 * 32 + b], vD1);
      vD2 = fmaf(r, g[7 * 32 + b], vD2);
      vE0 = fmaf(r, g[8 * 32 + b], vE0);
      vE1 = fmaf(r, g[9 * 32 + b], vE1);
      vE2 = fmaf(r, g[10 * 32 + b], vE2);
    }
    y0 += sA + vB0 * ux + vB1 * uy + vB2 * uz;
    t0 += sC * ux + vD0 + (vE1 * uz - vE2 * uy);
    t1 += sC * uy + vD1 + (vE2 * ux - vE0 * uz);
    t2 += sC * uz + vD2 + (vE0 * uy - vE1 * ux);
  }
  float4* pb = (float4*)(wso + WS_PB);
  pb[i * 96 + chunk] = make_float4(y0, t0, t1, t2);   // [i][chunk]
}

// ------------------------------------------------------------------
__global__ __launch_bounds__(64) void k_passB2(float* __restrict__ ws, void* out, int it) {
  int i = blockIdx.x * 64 + threadIdx.x;
  int bf = (int)ws[WS_MODE];
  const float4* pb = (const float4*)(ws + WS_PB);
  float ax = 0.f, ay = 0.f, az = 0.f, aw = 0.f;
#pragma unroll 8
  for (int c = 0; c < 96; ++c) {
    float4 v = pb[i * 96 + c];
    ax += v.x; ay += v.y; az += v.z; aw += v.w;
  }
  float y0 = ax + ws[WS_B1L0];
  float sg = expf(y0);
  float s2 = sg * sg;
  float lnrm = 0.5f * logf(6.2831855f * s2);
  const uint32_t* hk = (const uint32_t*)(ws + WS_HKEY);
  uint32_t h0 = hk[it * 2 + 0], h1 = hk[it * 2 + 1];
  float base[3] = {ws[WS_PX + i], ws[WS_PY + i], ws[WS_PZ + i]};
  float tr[3] = {ay, az, aw};
  float logp = 0.0f;
#pragma unroll
  for (int m = 0; m < 3; ++m) {
    float mu = base[m] + tr[m];
    int f = i * 3 + m;
    uint32_t o0, o1;
    tf2x32(h0, h1, 0u, (uint32_t)f, o0, o1);
    uint32_t bits = o0 ^ o1;                     // partitionable 32-bit fold
    float u1 = __uint_as_float((bits >> 9) | 0x3f800000u) - 1.0f;
    const float lo = -0.99999994f;
    float u = fmaxf(lo, u1 * 2.0f + lo);
    float nz = 1.41421354f * erfinv_f(u);
    float oy = mu + nz * sg;
    float d = oy - mu;
    logp -= lnrm + (d * d) / (2.0f * s2);
    if (m == 0) ws[WS_PX + i] = oy;
    else if (m == 1) ws[WS_PY + i] = oy;
    else ws[WS_PZ + i] = oy;
    store_out(out, OUT_YS + (it + 1) * 2304 + i * 3 + m, oy, bf);
    if (it == 1) store_out(out, i * 3 + m, oy, bf);
  }
  ws[WS_LG + it * 768 + i] = logp;
}

// ------------------------------------------------------------------
__global__ void k_logp(float* __restrict__ ws, void* out) {
  __shared__ float red[256];
  int t = threadIdx.x;
  float s = 0.0f;
  for (int e = t; e < 1536; e += 256) s += ws[WS_LG + e];
  red[t] = s;
  __syncthreads();
  for (int off = 128; off; off >>= 1) {
    if (t < off) red[t] += red[t + off];
    __syncthreads();
  }
  if (t == 0) store_out(out, OUT_LOGP, red[0], (int)ws[WS_MODE]);
}

// ------------------------------------------------------------------
extern "C" void kernel_launch(void* const* d_in, const int* in_sizes, int n_in,
                              void* d_out, int out_size, void* d_ws, size_t ws_size,
                              hipStream_t stream) {
  (void)in_sizes; (void)n_in; (void)out_size; (void)ws_size;
  float* ws = (float*)d_ws;
  k_init<<<16, 256, 0, stream>>>(d_in[0], d_in[1], d_in[2], d_in[3], d_in[4], d_in[5],
                                 d_in[6], d_in[7], d_in[8], d_in[9], d_in[10],
                                 d_in[11], d_in[12], d_in[13], d_in[14], d_in[15],
                                 d_in[16], d_in[17], d_in[18], (const int*)d_in[19],
                                 ws, d_out);
  for (int it = 0; it < 2; ++it) {
    k_passA<<<dim3(768, 3, 2), 256, 0, stream>>>(ws, ws, it);
    k_passA2<<<768, 64, 0, stream>>>(ws, ws);
    k_passB<<<dim3(96, 12), 64, 0, stream>>>(ws, ws);
    k_passB2<<<12, 64, 0, stream>>>(ws, d_out, it);
  }
  k_logp<<<1, 256, 0, stream>>>(ws, d_out);
}